// Round 12
// baseline (261.966 us; speedup 1.0000x reference)
//
#include <hip/hip_runtime.h>
#include <hip/hip_bf16.h>

#define N_NODES 20000
#define NEDGE   320000
#define DIM     128
#define NH      4
#define HD      512   // NH*DIM
#define LAYERS  3
#define EPS_RMS 1.1920929e-07f
#define SLOPE   0.2f
#define NTILES  (N_NODES >> 4)   // 1250

#define NVC   (LAYERS * DIM)         // 384
#define NXV   (N_NODES * DIM / 8)    // 320000 vec8 items
#define NWG8  (LAYERS * 512 * 16)    // 24576 v8 pack items (Wmix)
#define NW18  (LAYERS * 128 * 16)    // 6144 v8 pack items (W1 or W2)
#define NPACK8 (NWG8 + 2 * NW18 + 5 * NVC)   // 38784

typedef __bf16 bf16_t;
typedef __bf16 bf16v2 __attribute__((ext_vector_type(2)));
typedef __bf16 bf16v8 __attribute__((ext_vector_type(8)));
typedef float  f32v4  __attribute__((ext_vector_type(4)));
typedef float  f32v2  __attribute__((ext_vector_type(2)));

__device__ __forceinline__ int clamp_node(int s) {
    return ((unsigned)s >= (unsigned)N_NODES) ? 0 : s;
}
__device__ __forceinline__ float leaky(float e) { return e > 0.f ? e : SLOPE * e; }
__device__ __forceinline__ unsigned char enc_fp8(float v) {
    int p = __builtin_amdgcn_cvt_pk_fp8_f32(v, v, 0, false);
    return (unsigned char)(p & 0xff);
}
__device__ __forceinline__ unsigned short enc_fp8_pair(float a, float b) {
    int p = __builtin_amdgcn_cvt_pk_fp8_f32(a, b, 0, false);
    return (unsigned short)(p & 0xffff);
}

// ---- register-only DPP reductions (no LDS traffic) ----
template <int CTRL>
__device__ __forceinline__ float dpp_add(float x) {
    int v = __builtin_amdgcn_update_dpp(0, __float_as_int(x), CTRL, 0xF, 0xF, true);
    return x + __int_as_float(v);
}
// sum over each aligned 16-lane row; every lane gets the row sum
__device__ __forceinline__ float red16(float x) {
    x = dpp_add<0xB1>(x);    // xor1 (quad_perm [1,0,3,2])
    x = dpp_add<0x4E>(x);    // xor2 (quad_perm [2,3,0,1])
    x = dpp_add<0x124>(x);   // row_ror:4
    x = dpp_add<0x128>(x);   // row_ror:8
    return x;
}
// sum over all 64 lanes; every lane gets the sum (only 2 LDS ops)
__device__ __forceinline__ float red64(float x) {
    x = red16(x);
    x += __shfl_xor(x, 16);
    x += __shfl_xor(x, 32);
    return x;
}

// ---- uniform-index lane broadcast on the VALU pipe (v_readlane, zero LDS) ----
__device__ __forceinline__ float rlf(float x, int l) {
    return __int_as_float(__builtin_amdgcn_readlane(__float_as_int(x), l));
}

// ---- per-wave dtype detection ----
__device__ __forceinline__ bool wave_detect_bf16(const unsigned short* xh) {
    int lane = threadIdx.x & 63;
    unsigned short hw = xh[2 * lane];
    int e = (hw >> 7) & 0xff;
    unsigned long long b = __ballot(e >= 96 && e <= 140);
    return __popcll(b) >= 48;
}
__device__ __forceinline__ bool wave_detect_i64(const int* ei) {
    int lane = threadIdx.x & 63;
    unsigned long long b = __ballot(ei[2 * lane + 1] != 0);
    return b == 0ULL;
}
__device__ __forceinline__ float raw_elem(const void* in, size_t j, bool isbf) {
    return isbf ? (float)((const bf16_t*)in)[j] : ((const float*)in)[j];
}
__device__ __forceinline__ bf16_t cvt_elem(const void* in, size_t j, bool isbf) {
    return isbf ? ((const bf16_t*)in)[j] : (bf16_t)((const float*)in)[j];
}
__device__ __forceinline__ int edge_src(const int* ei, int e, bool is64) {
    return clamp_node(is64 ? ei[2 * e] : ei[e]);
}
__device__ __forceinline__ int edge_dst(const int* ei, int e, bool is64) {
    return clamp_node(is64 ? ei[2 * NEDGE + 2 * e] : ei[NEDGE + e]);
}

// ---------------- prep_v (+ deg zeroing) ----------------
__global__ __launch_bounds__(256) void prep_v(const void* x, const void* Wg,
                                              const void* aS, const void* aD,
                                              float* __restrict__ vS, float* __restrict__ vD,
                                              int* __restrict__ deg) {
    int gid = blockIdx.x * 256 + threadIdx.x;
    for (int i = gid; i < N_NODES; i += gridDim.x * 256) deg[i] = 0;
    bool isbf = wave_detect_bf16((const unsigned short*)x);
    int w = gid >> 6;
    if (w >= LAYERS * DIM * NH * 2) return;
    int lane = threadIdx.x & 63;
    int sd = w & 1, h = (w >> 1) & 3, k = (w >> 3) & 127, l = w >> 10;
    const void* att = sd ? aD : aS;
    size_t wbase = (size_t)l * DIM * HD + (size_t)k * HD + h * DIM;
    size_t abase = (size_t)l * NH * DIM + (size_t)h * DIM;
    int c = 2 * lane;
    float p = raw_elem(Wg, wbase + c, isbf) * raw_elem(att, abase + c, isbf)
            + raw_elem(Wg, wbase + c + 1, isbf) * raw_elem(att, abase + c + 1, isbf);
    p = red64(p);
    if (lane == 0) {
        float* dst = sd ? vD : vS;
        dst[l * HD + h * DIM + k] = p;
    }
}

// ---- read 8 consecutive source elements (bf16 or f32) as bf16 ----
__device__ __forceinline__ void read8(const void* src, size_t off, bool isbf, bf16_t (&v)[8]) {
    if (isbf) {
        bf16v8 a = *reinterpret_cast<const bf16v8*>((const bf16_t*)src + off);
#pragma unroll
        for (int n = 0; n < 8; ++n) v[n] = a[n];
    } else {
        float4 a = *reinterpret_cast<const float4*>((const float*)src + off);
        float4 b = *reinterpret_cast<const float4*>((const float*)src + off + 4);
        v[0] = (bf16_t)a.x; v[1] = (bf16_t)a.y; v[2] = (bf16_t)a.z; v[3] = (bf16_t)a.w;
        v[4] = (bf16_t)b.x; v[5] = (bf16_t)b.y; v[6] = (bf16_t)b.z; v[7] = (bf16_t)b.w;
    }
}

// ---- coalesced fragment-pack: item = 8 consecutive COLUMNS of one weight row ----
__device__ __forceinline__ void pack8(int t, bool isbf,
        const void* Wg, const void* W1, const void* W2,
        const void* bg, const void* b1, const void* b2,
        const void* n1, const void* n2,
        bf16_t* WmixP, bf16_t* W1P, bf16_t* W2P,
        bf16_t* bgc, bf16_t* b1c, bf16_t* b2c, bf16_t* n1c, bf16_t* n2c) {
    if (t < NWG8) {   // Wmix: per l, 512 kidx x 16 col-groups
        int l = t >> 13;              // /8192
        int r = t & 8191;
        int kidx = r >> 4;            // 0..511
        int c0 = (r & 15) * 8;        // 0..120
        int h = kidx >> 7, kp = kidx & 127;
        int kk = kidx >> 5, kqq = (kidx >> 3) & 3, j = kidx & 7;
        int wvv = c0 >> 5, tt = (c0 >> 4) & 1, mm0 = c0 & 15;
        size_t src = (size_t)l * DIM * HD + (size_t)kp * HD + h * DIM + c0;
        int base = (l << 16) + (((wvv * 16 + kk) * 2 + tt) << 9) + (kqq * 16 + mm0) * 8 + j;
        bf16_t v[8];
        read8(Wg, src, isbf, v);
#pragma unroll
        for (int n = 0; n < 8; ++n) WmixP[base + n * 8] = v[n];
        return;
    }
    t -= NWG8;
    if (t < 2 * NW18) {   // W1 / W2: per l, 128 k x 16 col-groups
        const void* Wsrc = (t < NW18) ? W1 : W2;
        bf16_t* Wdst = (t < NW18) ? W1P : W2P;
        if (t >= NW18) t -= NW18;
        int l = t >> 11;              // /2048
        int r = t & 2047;
        int k = r >> 4;               // 0..127
        int c0 = (r & 15) * 8;
        int ks = k >> 5, kqq = (k >> 3) & 3, j = k & 7;
        int wvv = c0 >> 5, tt = (c0 >> 4) & 1, mm0 = c0 & 15;
        size_t src = (size_t)l * DIM * DIM + (size_t)k * DIM + c0;
        int base = (l << 14) + (((wvv * 4 + ks) * 2 + tt) << 9) + (kqq * 16 + mm0) * 8 + j;
        bf16_t v[8];
        read8(Wsrc, src, isbf, v);
#pragma unroll
        for (int n = 0; n < 8; ++n) Wdst[base + n * 8] = v[n];
        return;
    }
    t -= 2 * NW18;
    if (t >= 5 * NVC) return;
    int seg = t / NVC, k = t - seg * NVC;
    if (seg == 0) bgc[k] = cvt_elem(bg, k, isbf);
    else if (seg == 1) b1c[k] = cvt_elem(b1, k, isbf);
    else if (seg == 2) b2c[k] = cvt_elem(b2, k, isbf);
    else if (seg == 3) n1c[k] = cvt_elem(n1, k, isbf);
    else n2c[k] = cvt_elem(n2, k, isbf);
}

// ---------------- mega: vec-convert(+coalesced pack) + hist + asd_x8 ----------------
__global__ __launch_bounds__(256) void mega_setup(
        const void* x, const void* Wg, const void* W1, const void* W2,
        const void* bg, const void* b1, const void* b2, const void* n1, const void* n2,
        bf16_t* xb, bf16_t* WmixP, bf16_t* W1P, bf16_t* W2P,
        bf16_t* bgc, bf16_t* b1c, bf16_t* b2c, bf16_t* n1c, bf16_t* n2c,
        const int* ei, int* deg,
        const float* vS, const float* vD,
        float* a_s, float* a_d, unsigned short* x8,
        int convBlocks, int histBlocks) {
    int b = (int)blockIdx.x;
    if (b >= convBlocks + histBlocks) {   // asd_x8 part: wave per node
        bool isbf = wave_detect_bf16((const unsigned short*)x);
        int lane = threadIdx.x & 63;
        int n = (b - convBlocks - histBlocks) * 4 + (int)(threadIdx.x >> 6);
        if (n >= N_NODES) return;
        int c = 2 * lane;
        float f0 = raw_elem(x, (size_t)n * DIM + c, isbf);
        float f1 = raw_elem(x, (size_t)n * DIM + c + 1, isbf);
        x8[n * 64 + lane] = enc_fp8_pair(f0, f1);
#pragma unroll
        for (int h = 0; h < NH; ++h) {
            float ps = f0 * vS[h * DIM + c] + f1 * vS[h * DIM + c + 1];
            float pd = f0 * vD[h * DIM + c] + f1 * vD[h * DIM + c + 1];
            ps = red64(ps);
            pd = red64(pd);
            if (lane == 0) {
                a_s[n * 4 + h] = ps;
                a_d[n * 4 + h] = pd;
            }
        }
        return;
    }
    if (b >= convBlocks) {   // histogram
        bool is64 = wave_detect_i64(ei);
        int e = (b - convBlocks) * 256 + threadIdx.x;
        if (e < NEDGE) atomicAdd(&deg[edge_dst(ei, e, is64)], 1);
        return;
    }
    bool isbf = wave_detect_bf16((const unsigned short*)x);
    int i = b * 256 + threadIdx.x;
    if (i < NXV) {   // vectorized x -> bf16 convert (16B/lane)
        if (isbf) {
            ((bf16v8*)xb)[i] = ((const bf16v8*)x)[i];
        } else {
            const float4* src = (const float4*)x;
            float4 a = src[2 * i], bq = src[2 * i + 1];
            bf16v8 o;
            o[0] = (bf16_t)a.x;  o[1] = (bf16_t)a.y;
            o[2] = (bf16_t)a.z;  o[3] = (bf16_t)a.w;
            o[4] = (bf16_t)bq.x; o[5] = (bf16_t)bq.y;
            o[6] = (bf16_t)bq.z; o[7] = (bf16_t)bq.w;
            ((bf16v8*)xb)[i] = o;
        }
        return;
    }
    pack8(i - NXV, isbf, Wg, W1, W2, bg, b1, b2, n1, n2,
          WmixP, W1P, W2P, bgc, b1c, b2c, n1c, n2c);
}

// ---------------- scan: one-pass, 20 nodes per thread, 2 barriers total ----------------
__global__ __launch_bounds__(1024) void scan_kernel(const int* __restrict__ deg,
                                                    int* __restrict__ row_ptr,
                                                    int* __restrict__ cursor) {
    __shared__ int wsum[16];
    int tid = threadIdx.x, lane = tid & 63, wv = tid >> 6;
    int v[20];
    int base = tid * 20;
    int tot = 0;
    if (base < N_NODES) {
        const int4* d4 = reinterpret_cast<const int4*>(deg + base);   // 80B-aligned
#pragma unroll
        for (int j = 0; j < 5; ++j) {
            int4 q = d4[j];
            v[4 * j]     = q.x;
            v[4 * j + 1] = q.y;
            v[4 * j + 2] = q.z;
            v[4 * j + 3] = q.w;
        }
#pragma unroll
        for (int i = 0; i < 20; ++i) tot += v[i];
    }
    int x = tot;   // inclusive wave scan
#pragma unroll
    for (int off = 1; off < 64; off <<= 1) {
        int t = __shfl_up(x, off);
        if (lane >= off) x += t;
    }
    if (lane == 63) wsum[wv] = x;
    __syncthreads();
    if (wv == 0) {
        int s = (lane < 16) ? wsum[lane] : 0;
#pragma unroll
        for (int off = 1; off < 16; off <<= 1) {
            int t = __shfl_up(s, off);
            if (lane >= off) s += t;
        }
        if (lane < 16) wsum[lane] = s;
    }
    __syncthreads();
    int off0 = ((wv == 0) ? 0 : wsum[wv - 1]) + (x - tot);   // exclusive prefix of chunk
    if (tid == 0) row_ptr[0] = 0;
    if (base < N_NODES) {
        int run = off0;
#pragma unroll
        for (int i = 0; i < 20; ++i) {
            run += v[i];
            row_ptr[base + i + 1] = run;
            cursor[base + i] = run - v[i];
        }
    }
}

__global__ void fill_kernel(const int* __restrict__ ei, int* __restrict__ cursor,
                            int* __restrict__ csr_src) {
    bool is64 = wave_detect_i64(ei);
    int e = blockIdx.x * blockDim.x + threadIdx.x;
    if (e < NEDGE) {
        int d = edge_dst(ei, e, is64);
        int pos = atomicAdd(&cursor[d], 1);
        if ((unsigned)pos < (unsigned)NEDGE) csr_src[pos] = edge_src(ei, e, is64);
    }
}

// ---- accumulate cnt (<=64) edges via v_readlane broadcast (ZERO LDS traffic) ----
// wl = this lane's edge weight (4 heads); sb6 = this lane's edge source-row base (s<<6).
// Depth-2 x8 prefetch retained (xA/xB static double-buffer).
__device__ __forceinline__ void acc_group_loop(float (&acc)[8], int cnt,
        float4 wl, int sb6,
        const unsigned short* __restrict__ x8, int lane) {
    unsigned short xA[8], xB[8];
    {
        int pa = cnt < 8 ? cnt : 8;
        int pb = cnt - 8; if (pb > 8) pb = 8;
#pragma unroll
        for (int u = 0; u < 8; ++u)
            if (u < pa) xA[u] = x8[__builtin_amdgcn_readlane(sb6, u) + lane];
#pragma unroll
        for (int u = 0; u < 8; ++u)
            if (u < pb) xB[u] = x8[__builtin_amdgcn_readlane(sb6, 8 + u) + lane];
    }
    for (int u0 = 0; u0 < cnt; u0 += 16) {
        {   // consume A = group u0; refill A with group u0+16
            unsigned short xc[8];
#pragma unroll
            for (int u = 0; u < 8; ++u) xc[u] = xA[u];
            int g = u0 + 16;
            int nc = cnt - g; if (nc > 8) nc = 8;
#pragma unroll
            for (int u = 0; u < 8; ++u)
                if (u < nc) xA[u] = x8[__builtin_amdgcn_readlane(sb6, g + u) + lane];
            int uc = cnt - u0; if (uc > 8) uc = 8;
#pragma unroll
            for (int u = 0; u < 8; ++u) {
                if (u < uc) {
                    int e = u0 + u;
                    float w0 = rlf(wl.x, e), w1 = rlf(wl.y, e),
                          w2 = rlf(wl.z, e), w3 = rlf(wl.w, e);
                    f32v2 f = __builtin_amdgcn_cvt_pk_f32_fp8((int)xc[u], false);
                    acc[0] += w0 * f[0]; acc[1] += w0 * f[1];
                    acc[2] += w1 * f[0]; acc[3] += w1 * f[1];
                    acc[4] += w2 * f[0]; acc[5] += w2 * f[1];
                    acc[6] += w3 * f[0]; acc[7] += w3 * f[1];
                }
            }
        }
        if (u0 + 8 < cnt) {   // consume B = group u0+8; refill B with group u0+24
            unsigned short xc[8];
#pragma unroll
            for (int u = 0; u < 8; ++u) xc[u] = xB[u];
            int g = u0 + 24;
            int nc = cnt - g; if (nc > 8) nc = 8;
#pragma unroll
            for (int u = 0; u < 8; ++u)
                if (u < nc) xB[u] = x8[__builtin_amdgcn_readlane(sb6, g + u) + lane];
            int uc = cnt - (u0 + 8); if (uc > 8) uc = 8;
#pragma unroll
            for (int u = 0; u < 8; ++u) {
                if (u < uc) {
                    int e = u0 + 8 + u;
                    float w0 = rlf(wl.x, e), w1 = rlf(wl.y, e),
                          w2 = rlf(wl.z, e), w3 = rlf(wl.w, e);
                    f32v2 f = __builtin_amdgcn_cvt_pk_f32_fp8((int)xc[u], false);
                    acc[0] += w0 * f[0]; acc[1] += w0 * f[1];
                    acc[2] += w1 * f[0]; acc[3] += w1 * f[1];
                    acc[4] += w2 * f[0]; acc[5] += w2 * f[1];
                    acc[6] += w3 * f[0]; acc[7] += w3 * f[1];
                }
            }
        }
    }
}

// ---------------- gat_phaseA: software-pipelined 4-node gather (rows chosen by caller) ----------------
// Prologue issues ALL independent front-end loads upfront; only the per-node a_s[s]
// gather is staged one-ahead. Edge broadcast via v_readlane -> zero gather-loop LDS.
__device__ __forceinline__ void gat_phaseA(int tile, int lane, const int rw[4],
        const int* __restrict__ row_ptr, const int* __restrict__ csr_src,
        const float* __restrict__ a_s, const float* __restrict__ a_d,
        const unsigned short* __restrict__ x8, bf16_t (*ylds)[524]) {
    const float4* a_s4 = reinterpret_cast<const float4*>(a_s);
    const float4* a_d4 = reinterpret_cast<const float4*>(a_d);

    // all row_ptr loads upfront (independent)
    int beg[4], deg[4];
#pragma unroll
    for (int rp = 0; rp < 4; ++rp) {
        int nn = tile * 16 + rw[rp];
        int b = row_ptr[nn], e = row_ptr[nn + 1];
        int d = e - b;
        if (d < 0) d = 0;
        if (d > NEDGE) d = NEDGE;
        if (b < 0) b = 0;
        if (b > NEDGE - d) b = NEDGE - d;
        beg[rp] = b; deg[rp] = d;
    }

    int craw[4], sreg[4];
    unsigned short pslf[4];
    float4 av4[4], adv4[4], avs4[4];

    // prologue: ALL independent loads in flight at once
#pragma unroll
    for (int rp = 0; rp < 4; ++rp) {
        int d = deg[rp];
        int idx = (d > 0) ? (beg[rp] + (lane < d ? lane : 0)) : 0;
        craw[rp] = csr_src[idx];
    }
#pragma unroll
    for (int rp = 0; rp < 4; ++rp) {
        int nn = tile * 16 + rw[rp];
        adv4[rp] = a_d4[nn];
        avs4[rp] = a_s4[nn];
        pslf[rp] = x8[nn * 64 + lane];
    }
    {
        int s = clamp_node(craw[0]);
        sreg[0] = s;
        av4[0] = a_s4[s];           // exposed once per wave (prologue only)
    }

#pragma unroll
    for (int rp = 0; rp < 4; ++rp) {
        // ---- W(rp): weights + init (av issued >=1 stage earlier) ----
        float4 adv = adv4[rp];
        float4 a0 = av4[rp];
        float4 wl = {__expf(leaky(a0.x + adv.x)), __expf(leaky(a0.y + adv.y)),
                     __expf(leaky(a0.z + adv.z)), __expf(leaky(a0.w + adv.w))};
        float4 avs = avs4[rp];
        float4 wself = {__expf(leaky(avs.x + adv.x)), __expf(leaky(avs.y + adv.y)),
                        __expf(leaky(avs.z + adv.z)), __expf(leaky(avs.w + adv.w))};
        float acc[8];
        {
            f32v2 f = __builtin_amdgcn_cvt_pk_f32_fp8((int)pslf[rp], false);
            acc[0] = wself.x * f[0]; acc[1] = wself.x * f[1];
            acc[2] = wself.y * f[0]; acc[3] = wself.y * f[1];
            acc[4] = wself.z * f[0]; acc[5] = wself.z * f[1];
            acc[6] = wself.w * f[0]; acc[7] = wself.w * f[1];
        }
        int cnt0 = deg[rp] < 64 ? deg[rp] : 64;
        float4 zl = {0.f, 0.f, 0.f, 0.f};
        if (lane < cnt0) zl = wl;
        int sb6 = sreg[rp] << 6;

        // ---- F(rp+1): issue next node's a_s[s] gather (hides under ACC below) ----
        if (rp < 3) {
            int s = clamp_node(craw[rp + 1]);
            sreg[rp + 1] = s;
            av4[rp + 1] = a_s4[s];
        }

        // ---- ACC(rp): first chunk via readlane broadcast (no LDS) ----
        acc_group_loop(acc, cnt0, wl, sb6, x8, lane);

        // ---- tail chunks (deg > 64, rare): inline front-end + readlane ----
        for (int c0 = 64; c0 < deg[rp]; c0 += 64) {
            int cnt = deg[rp] - c0; if (cnt > 64) cnt = 64;
            float4 w2 = {0.f, 0.f, 0.f, 0.f};
            int sb2 = 0;
            if (lane < cnt) {
                int s = clamp_node(csr_src[beg[rp] + c0 + lane]);
                float4 a2 = a_s4[s];
                w2 = (float4){__expf(leaky(a2.x + adv.x)), __expf(leaky(a2.y + adv.y)),
                              __expf(leaky(a2.z + adv.z)), __expf(leaky(a2.w + adv.w))};
                zl.x += w2.x; zl.y += w2.y; zl.z += w2.z; zl.w += w2.w;
                sb2 = s << 6;
            }
            acc_group_loop(acc, cnt, w2, sb2, x8, lane);
        }

        // ---- Z-reduce (DPP) + y write ----
        float4 z4 = {wself.x + red64(zl.x), wself.y + red64(zl.y),
                     wself.z + red64(zl.z), wself.w + red64(zl.w)};
        float4 ih4 = {1.f / z4.x, 1.f / z4.y, 1.f / z4.z, 1.f / z4.w};
        int c = 2 * lane;
        bf16_t* yrow = &ylds[rw[rp]][0];
#pragma unroll
        for (int h = 0; h < NH; ++h) {
            float ih = h == 0 ? ih4.x : h == 1 ? ih4.y : h == 2 ? ih4.z : ih4.w;
            bf16v2 o;
            o[0] = (bf16_t)(acc[h * 2 + 0] * ih);
            o[1] = (bf16_t)(acc[h * 2 + 1] * ih);
            *reinterpret_cast<bf16v2*>(&yrow[h * DIM + c]) = o;
        }
    }
}

// ---------------- gat_mix: fused per-layer kernel; block = 16 nodes ----------------
// Phase A: degree-balanced pipelined 4-node gather (readlane broadcast, zero LDS).
// Phase B: proven mix+FFN with DPP 16-lane reductions.
// MODE 0: writes bf16 xb + next-layer x8/a_s/a_d.  MODE 1: writes f32 d_out.
template <int MODE>
__global__ __launch_bounds__(256) void gat_mix(
        const int* __restrict__ row_ptr, const int* __restrict__ csr_src,
        const float* __restrict__ a_s, const float* __restrict__ a_d,
        const unsigned short* __restrict__ x8,
        const bf16_t* __restrict__ WmixP, const bf16_t* __restrict__ bg,
        const bf16_t* __restrict__ n1w, const bf16_t* __restrict__ xb,
        const bf16_t* __restrict__ W1P, const bf16_t* __restrict__ b1,
        const bf16_t* __restrict__ W2P, const bf16_t* __restrict__ b2,
        const bf16_t* __restrict__ n2w, void* __restrict__ out,
        const float* __restrict__ vS, const float* __restrict__ vD,
        float* __restrict__ a_s_n, float* __restrict__ a_d_n,
        unsigned char* __restrict__ x8_n) {
    __shared__ bf16_t ylds[16][524];
    __shared__ bf16_t xm[16][140];
    __shared__ float  ssq_p[16][4];
    __shared__ float  asd_p[4][16][8];
    bf16_t (*hh)[140] = reinterpret_cast<bf16_t (*)[140]>(&ylds[0][0]);

    int tile = blockIdx.x;
    int wv = threadIdx.x >> 6;
    int lane = threadIdx.x & 63;
    int m = lane & 15, kq = lane >> 4;

    // ---- degree-balanced row assignment: rank 16 rows by degree (shfl), snake-deal ----
    int rw[4];
    {
        int d = 0;
        if (lane < 16) {
            int nn = tile * 16 + lane;
            d = row_ptr[nn + 1] - row_ptr[nn];
        }
        int rank = 0;
#pragma unroll
        for (int j = 0; j < 16; ++j) {
            int dj = __shfl(d, j);
            rank += ((dj > d) || (dj == d && j < lane)) ? 1 : 0;
        }
        if (lane >= 16) rank = 64;   // exclude from matches
        int tgt0 = wv, tgt1 = 7 - wv, tgt2 = 8 + wv, tgt3 = 15 - wv;
        rw[0] = __ffsll(__ballot(rank == tgt0)) - 1;
        rw[1] = __ffsll(__ballot(rank == tgt1)) - 1;
        rw[2] = __ffsll(__ballot(rank == tgt2)) - 1;
        rw[3] = __ffsll(__ballot(rank == tgt3)) - 1;
    }

    // ---- Phase A ----
    gat_phaseA(tile, lane, rw, row_ptr, csr_src, a_s, a_d, x8, ylds);
    __syncthreads();

    // ---- Phase B: mix + FFN ----
    f32v4 accm[2];
    accm[0] = (f32v4){0.f, 0.f, 0.f, 0.f};
    accm[1] = (f32v4){0.f, 0.f, 0.f, 0.f};
#pragma unroll
    for (int kk = 0; kk < 16; ++kk) {
        bf16v8 a = *reinterpret_cast<const bf16v8*>(&ylds[m][kk * 32 + kq * 8]);
#pragma unroll
        for (int tt = 0; tt < 2; ++tt) {
            bf16v8 b = *reinterpret_cast<const bf16v8*>(
                WmixP + ((((wv * 16 + kk) * 2 + tt) << 9) + lane * 8));
            accm[tt] = __builtin_amdgcn_mfma_f32_16x16x32_bf16(a, b, accm[tt], 0, 0, 0);
        }
    }
    float vals[2][4];
    {
        float sp[4] = {0.f, 0.f, 0.f, 0.f};
#pragma unroll
        for (int tt = 0; tt < 2; ++tt) {
            int col = 32 * wv + tt * 16 + m;
            float bv = (float)bg[col];
#pragma unroll
            for (int r = 0; r < 4; ++r) {
                int gr = tile * 16 + kq * 4 + r;
                float v = 0.25f * accm[tt][r] + bv + (float)xb[(size_t)gr * DIM + col];
                vals[tt][r] = v;
                sp[r] += v * v;
            }
        }
#pragma unroll
        for (int r = 0; r < 4; ++r) {
            sp[r] = red16(sp[r]);
            if (m == r) ssq_p[kq * 4 + r][wv] = sp[r];
        }
    }
    __syncthreads();
    {
#pragma unroll
        for (int r = 0; r < 4; ++r) {
            int row = kq * 4 + r;
            float s = ssq_p[row][0] + ssq_p[row][1] + ssq_p[row][2] + ssq_p[row][3];
            float scale = rsqrtf(s * (1.f / 128.f) + EPS_RMS);
#pragma unroll
            for (int tt = 0; tt < 2; ++tt) {
                int col = 32 * wv + tt * 16 + m;
                xm[row][col] = (bf16_t)(vals[tt][r] * scale * (float)n1w[col]);
            }
        }
    }
    __syncthreads();

    f32v4 acc1[2];
    acc1[0] = (f32v4){0.f, 0.f, 0.f, 0.f};
    acc1[1] = (f32v4){0.f, 0.f, 0.f, 0.f};
#pragma unroll
    for (int ks = 0; ks < 4; ++ks) {
        bf16v8 a = *reinterpret_cast<const bf16v8*>(&xm[m][ks * 32 + kq * 8]);
#pragma unroll
        for (int tt = 0; tt < 2; ++tt) {
            bf16v8 b = *reinterpret_cast<const bf16v8*>(
                W1P + ((((wv * 4 + ks) * 2 + tt) << 9) + lane * 8));
            acc1[tt] = __builtin_amdgcn_mfma_f32_16x16x32_bf16(a, b, acc1[tt], 0, 0, 0);
        }
    }
#pragma unroll
    for (int tt = 0; tt < 2; ++tt) {
        int col = 32 * wv + tt * 16 + m;
        float bv = (float)b1[col];
#pragma unroll
        for (int r = 0; r < 4; ++r) {
            float v = acc1[tt][r] + bv;
            hh[kq * 4 + r][col] = (bf16_t)(v > 0.f ? v : 0.f);
        }
    }
    __syncthreads();
    f32v4 acc2[2];
    acc2[0] = (f32v4){0.f, 0.f, 0.f, 0.f};
    acc2[1] = (f32v4){0.f, 0.f, 0.f, 0.f};
#pragma unroll
    for (int ks = 0; ks < 4; ++ks) {
        bf16v8 a = *reinterpret_cast<const bf16v8*>(&hh[m][ks * 32 + kq * 8]);
#pragma unroll
        for (int tt = 0; tt < 2; ++tt) {
            bf16v8 b = *reinterpret_cast<const bf16v8*>(
                W2P + ((((wv * 4 + ks) * 2 + tt) << 9) + lane * 8));
            acc2[tt] = __builtin_amdgcn_mfma_f32_16x16x32_bf16(a, b, acc2[tt], 0, 0, 0);
        }
    }
    float vals2[2][4];
    {
        float sp[4] = {0.f, 0.f, 0.f, 0.f};
#pragma unroll
        for (int tt = 0; tt < 2; ++tt) {
            int col = 32 * wv + tt * 16 + m;
            float bv = (float)b2[col];
#pragma unroll
            for (int r = 0; r < 4; ++r) {
                float v = acc2[tt][r] + bv + (float)xm[kq * 4 + r][col];
                vals2[tt][r] = v;
                sp[r] += v * v;
            }
        }
#pragma unroll
        for (int r = 0; r < 4; ++r) {
            sp[r] = red16(sp[r]);
            if (m == r) ssq_p[kq * 4 + r][wv] = sp[r];
        }
    }
    __syncthreads();
    float o2[2][4];
#pragma unroll
    for (int r = 0; r < 4; ++r) {
        int row = kq * 4 + r;
        int gr = tile * 16 + row;
        float s = ssq_p[row][0] + ssq_p[row][1] + ssq_p[row][2] + ssq_p[row][3];
        float scale = rsqrtf(s * (1.f / 128.f) + EPS_RMS);
#pragma unroll
        for (int tt = 0; tt < 2; ++tt) {
            int col = 32 * wv + tt * 16 + m;
            float o = vals2[tt][r] * scale * (float)n2w[col];
            o2[tt][r] = o;
            if (MODE == 1) ((float*)out)[(size_t)gr * DIM + col] = o;
            else {
                ((bf16_t*)out)[(size_t)gr * DIM + col] = (bf16_t)o;
                x8_n[(size_t)gr * DIM + col] = enc_fp8(o);
            }
        }
    }
    if (MODE == 0) {
        float vs0[NH], vs1[NH], vd0[NH], vd1[NH];
        int col0 = 32 * wv + m, col1 = col0 + 16;
#pragma unroll
        for (int h = 0; h < NH; ++h) {
            vs0[h] = vS[h * DIM + col0]; vs1[h] = vS[h * DIM + col1];
            vd0[h] = vD[h * DIM + col0]; vd1[h] = vD[h * DIM + col1];
        }
#pragma unroll
        for (int r = 0; r < 4; ++r) {
#pragma unroll
            for (int h = 0; h < NH; ++h) {
                float ps = o2[0][r] * vs0[h] + o2[1][r] * vs1[h];
                float pd = o2[0][r] * vd0[h] + o2[1][r] * vd1[h];
                ps = red16(ps);
                pd = red16(pd);
                if (m == r * 4 + h) {
                    asd_p[wv][kq * 4 + r][h * 2 + 0] = ps;
                    asd_p[wv][kq * 4 + r][h * 2 + 1] = pd;
                }
            }
        }
        __syncthreads();
        int t = threadIdx.x;
        if (t < 128) {
            int row = t >> 3, idx = t & 7;
            float s = asd_p[0][row][idx] + asd_p[1][row][idx]
                    + asd_p[2][row][idx] + asd_p[3][row][idx];
            int gr = tile * 16 + row;
            if (idx & 1) a_d_n[gr * 4 + (idx >> 1)] = s;
            else         a_s_n[gr * 4 + (idx >> 1)] = s;
        }
    }
}

// ---------------- launch (7 dispatches) ----------------
extern "C" void kernel_launch(void* const* d_in, const int* in_sizes, int n_in,
                              void* d_out, int out_size, void* d_ws, size_t ws_size,
                              hipStream_t stream) {
    const void* x_in   = d_in[0];
    const void* W_gat  = d_in[1];
    const void* att_s  = d_in[2];
    const void* att_d  = d_in[3];
    const void* bias_g = d_in[4];
    const void* W1     = d_in[5];
    const void* b1     = d_in[6];
    const void* W2     = d_in[7];
    const void* b2     = d_in[8];
    const void* n1w    = d_in[9];
    const void* n2w    = d_in[10];
    const int*  ei     = (const int*)d_in[11];

    char* ws = (char*)d_ws;
    size_t off = 0;
    auto alloc = [&](size_t bytes) {
        void* p = ws + off;
        off = (off + bytes + 255) & ~(size_t)255;
        return p;
    };
    bf16_t* WmixP   = (bf16_t*)alloc((size_t)LAYERS * HD * DIM * 2);
    bf16_t* W1P     = (bf16_t*)alloc((size_t)LAYERS * DIM * DIM * 2);
    bf16_t* W2P     = (bf16_t*)alloc((size_t)LAYERS * DIM * DIM * 2);
    bf16_t* xb      = (bf16_t*)alloc((size_t)N_NODES * DIM * 2);
    unsigned short* x8a = (unsigned short*)alloc((size_t)N_NODES * DIM);
    unsigned short* x8b = (unsigned short*)alloc((size_t)N_NODES * DIM);
    float*  vS      = (float*)alloc((size_t)LAYERS * HD * 4);
    float*  vD      = (float*)alloc((size_t)LAYERS * HD * 4);
    float*  a_sA    = (float*)alloc((size_t)N_NODES * NH * 4);
    float*  a_dA    = (float*)alloc((size_t)N_NODES * NH * 4);
    float*  a_sB    = (float*)alloc((size_t)N_NODES * NH * 4);
    float*  a_dB    = (float*)alloc((size_t)N_NODES * NH * 4);
    int*    deg     = (int*)alloc((size_t)N_NODES * 4);
    int*    cursor  = (int*)alloc((size_t)N_NODES * 4);
    int*    row_ptr = (int*)alloc((size_t)(N_NODES + 1) * 4);
    int*    csr     = (int*)alloc((size_t)NEDGE * 4);
    bf16_t* bgc     = (bf16_t*)alloc((size_t)LAYERS * DIM * 2);
    bf16_t* b1c     = (bf16_t*)alloc((size_t)LAYERS * DIM * 2);
    bf16_t* b2c     = (bf16_t*)alloc((size_t)LAYERS * DIM * 2);
    bf16_t* n1c     = (bf16_t*)alloc((size_t)LAYERS * DIM * 2);
    bf16_t* n2c     = (bf16_t*)alloc((size_t)LAYERS * DIM * 2);

    // prep_v also zeroes deg (runs before mega_setup's histogram)
    prep_v<<<(LAYERS * DIM * NH * 2 * 64 + 255) / 256, 256, 0, stream>>>(
        x_in, W_gat, att_s, att_d, vS, vD, deg);

    const int NTOT = NXV + NPACK8;   // vec8 convert items + coalesced pack items
    const int convBlocks = (NTOT + 255) / 256;
    const int histBlocks = (NEDGE + 255) / 256;
    const int asdBlocks  = (N_NODES + 3) / 4;
    mega_setup<<<convBlocks + histBlocks + asdBlocks, 256, 0, stream>>>(
        x_in, W_gat, W1, W2, bias_g, b1, b2, n1w, n2w,
        xb, WmixP, W1P, W2P, bgc, b1c, b2c, n1c, n2c,
        ei, deg, vS, vD, a_sA, a_dA, x8a, convBlocks, histBlocks);

    scan_kernel<<<1, 1024, 0, stream>>>(deg, row_ptr, cursor);
    fill_kernel<<<(NEDGE + 255) / 256, 256, 0, stream>>>(ei, cursor, csr);

    unsigned short* x8cur[2] = {x8a, x8b};
    float* asCur[2] = {a_sA, a_sB};
    float* adCur[2] = {a_dA, a_dB};
    for (int l = 0; l < LAYERS; ++l) {
        int ci = l & 1, ni = (l + 1) & 1;
        if (l < LAYERS - 1) {
            gat_mix<0><<<NTILES, 256, 0, stream>>>(
                row_ptr, csr, asCur[ci], adCur[ci], x8cur[ci],
                WmixP + (size_t)l * HD * DIM, bgc + (size_t)l * DIM,
                n1c + (size_t)l * DIM, xb,
                W1P + (size_t)l * DIM * DIM, b1c + (size_t)l * DIM,
                W2P + (size_t)l * DIM * DIM, b2c + (size_t)l * DIM,
                n2c + (size_t)l * DIM, xb,
                vS + (size_t)(l + 1) * HD, vD + (size_t)(l + 1) * HD,
                asCur[ni], adCur[ni], (unsigned char*)x8cur[ni]);
        } else {
            gat_mix<1><<<NTILES, 256, 0, stream>>>(
                row_ptr, csr, asCur[ci], adCur[ci], x8cur[ci],
                WmixP + (size_t)l * HD * DIM, bgc + (size_t)l * DIM,
                n1c + (size_t)l * DIM, xb,
                W1P + (size_t)l * DIM * DIM, b1c + (size_t)l * DIM,
                W2P + (size_t)l * DIM * DIM, b2c + (size_t)l * DIM,
                n2c + (size_t)l * DIM, d_out,
                nullptr, nullptr, nullptr, nullptr, nullptr);
        }
    }
}

// Round 13
// 253.420 us; speedup vs baseline: 1.0337x; 1.0337x over previous
//
#include <hip/hip_runtime.h>
#include <hip/hip_bf16.h>

#define N_NODES 20000
#define NEDGE   320000
#define DIM     128
#define NH      4
#define HD      512   // NH*DIM
#define LAYERS  3
#define EPS_RMS 1.1920929e-07f
#define SLOPE   0.2f
#define NTILES  (N_NODES >> 4)   // 1250

#define NVC   (LAYERS * DIM)         // 384
#define NXV   (N_NODES * DIM / 8)    // 320000 vec8 items
#define NWG8  (LAYERS * 512 * 16)    // 24576 v8 pack items (Wmix)
#define NW18  (LAYERS * 128 * 16)    // 6144 v8 pack items (W1 or W2)
#define NPACK8 (NWG8 + 2 * NW18 + 5 * NVC)   // 38784

typedef __bf16 bf16_t;
typedef __bf16 bf16v2 __attribute__((ext_vector_type(2)));
typedef __bf16 bf16v8 __attribute__((ext_vector_type(8)));
typedef float  f32v4  __attribute__((ext_vector_type(4)));
typedef float  f32v2  __attribute__((ext_vector_type(2)));

__device__ __forceinline__ int clamp_node(int s) {
    return ((unsigned)s >= (unsigned)N_NODES) ? 0 : s;
}
__device__ __forceinline__ float leaky(float e) { return e > 0.f ? e : SLOPE * e; }
__device__ __forceinline__ unsigned char enc_fp8(float v) {
    int p = __builtin_amdgcn_cvt_pk_fp8_f32(v, v, 0, false);
    return (unsigned char)(p & 0xff);
}
__device__ __forceinline__ unsigned short enc_fp8_pair(float a, float b) {
    int p = __builtin_amdgcn_cvt_pk_fp8_f32(a, b, 0, false);
    return (unsigned short)(p & 0xffff);
}

// ---- register-only DPP reductions (no LDS traffic) ----
template <int CTRL>
__device__ __forceinline__ float dpp_add(float x) {
    int v = __builtin_amdgcn_update_dpp(0, __float_as_int(x), CTRL, 0xF, 0xF, true);
    return x + __int_as_float(v);
}
// sum over each aligned 16-lane row; every lane gets the row sum
__device__ __forceinline__ float red16(float x) {
    x = dpp_add<0xB1>(x);    // xor1 (quad_perm [1,0,3,2])
    x = dpp_add<0x4E>(x);    // xor2 (quad_perm [2,3,0,1])
    x = dpp_add<0x124>(x);   // row_ror:4
    x = dpp_add<0x128>(x);   // row_ror:8
    return x;
}
// sum over all 64 lanes; every lane gets the sum (only 2 LDS ops)
__device__ __forceinline__ float red64(float x) {
    x = red16(x);
    x += __shfl_xor(x, 16);
    x += __shfl_xor(x, 32);
    return x;
}

// ---- per-wave dtype detection ----
__device__ __forceinline__ bool wave_detect_bf16(const unsigned short* xh) {
    int lane = threadIdx.x & 63;
    unsigned short hw = xh[2 * lane];
    int e = (hw >> 7) & 0xff;
    unsigned long long b = __ballot(e >= 96 && e <= 140);
    return __popcll(b) >= 48;
}
__device__ __forceinline__ bool wave_detect_i64(const int* ei) {
    int lane = threadIdx.x & 63;
    unsigned long long b = __ballot(ei[2 * lane + 1] != 0);
    return b == 0ULL;
}
__device__ __forceinline__ float raw_elem(const void* in, size_t j, bool isbf) {
    return isbf ? (float)((const bf16_t*)in)[j] : ((const float*)in)[j];
}
__device__ __forceinline__ bf16_t cvt_elem(const void* in, size_t j, bool isbf) {
    return isbf ? ((const bf16_t*)in)[j] : (bf16_t)((const float*)in)[j];
}
__device__ __forceinline__ int edge_src(const int* ei, int e, bool is64) {
    return clamp_node(is64 ? ei[2 * e] : ei[e]);
}
__device__ __forceinline__ int edge_dst(const int* ei, int e, bool is64) {
    return clamp_node(is64 ? ei[2 * NEDGE + 2 * e] : ei[NEDGE + e]);
}

// ---------------- prep_v (+ deg zeroing) ----------------
__global__ __launch_bounds__(256) void prep_v(const void* x, const void* Wg,
                                              const void* aS, const void* aD,
                                              float* __restrict__ vS, float* __restrict__ vD,
                                              int* __restrict__ deg) {
    int gid = blockIdx.x * 256 + threadIdx.x;
    for (int i = gid; i < N_NODES; i += gridDim.x * 256) deg[i] = 0;
    bool isbf = wave_detect_bf16((const unsigned short*)x);
    int w = gid >> 6;
    if (w >= LAYERS * DIM * NH * 2) return;
    int lane = threadIdx.x & 63;
    int sd = w & 1, h = (w >> 1) & 3, k = (w >> 3) & 127, l = w >> 10;
    const void* att = sd ? aD : aS;
    size_t wbase = (size_t)l * DIM * HD + (size_t)k * HD + h * DIM;
    size_t abase = (size_t)l * NH * DIM + (size_t)h * DIM;
    int c = 2 * lane;
    float p = raw_elem(Wg, wbase + c, isbf) * raw_elem(att, abase + c, isbf)
            + raw_elem(Wg, wbase + c + 1, isbf) * raw_elem(att, abase + c + 1, isbf);
    p = red64(p);
    if (lane == 0) {
        float* dst = sd ? vD : vS;
        dst[l * HD + h * DIM + k] = p;
    }
}

// ---- read 8 consecutive source elements (bf16 or f32) as bf16 ----
__device__ __forceinline__ void read8(const void* src, size_t off, bool isbf, bf16_t (&v)[8]) {
    if (isbf) {
        bf16v8 a = *reinterpret_cast<const bf16v8*>((const bf16_t*)src + off);
#pragma unroll
        for (int n = 0; n < 8; ++n) v[n] = a[n];
    } else {
        float4 a = *reinterpret_cast<const float4*>((const float*)src + off);
        float4 b = *reinterpret_cast<const float4*>((const float*)src + off + 4);
        v[0] = (bf16_t)a.x; v[1] = (bf16_t)a.y; v[2] = (bf16_t)a.z; v[3] = (bf16_t)a.w;
        v[4] = (bf16_t)b.x; v[5] = (bf16_t)b.y; v[6] = (bf16_t)b.z; v[7] = (bf16_t)b.w;
    }
}

// ---- coalesced fragment-pack: item = 8 consecutive COLUMNS of one weight row ----
__device__ __forceinline__ void pack8(int t, bool isbf,
        const void* Wg, const void* W1, const void* W2,
        const void* bg, const void* b1, const void* b2,
        const void* n1, const void* n2,
        bf16_t* WmixP, bf16_t* W1P, bf16_t* W2P,
        bf16_t* bgc, bf16_t* b1c, bf16_t* b2c, bf16_t* n1c, bf16_t* n2c) {
    if (t < NWG8) {   // Wmix: per l, 512 kidx x 16 col-groups
        int l = t >> 13;              // /8192
        int r = t & 8191;
        int kidx = r >> 4;            // 0..511
        int c0 = (r & 15) * 8;        // 0..120
        int h = kidx >> 7, kp = kidx & 127;
        int kk = kidx >> 5, kqq = (kidx >> 3) & 3, j = kidx & 7;
        int wvv = c0 >> 5, tt = (c0 >> 4) & 1, mm0 = c0 & 15;
        size_t src = (size_t)l * DIM * HD + (size_t)kp * HD + h * DIM + c0;
        int base = (l << 16) + (((wvv * 16 + kk) * 2 + tt) << 9) + (kqq * 16 + mm0) * 8 + j;
        bf16_t v[8];
        read8(Wg, src, isbf, v);
#pragma unroll
        for (int n = 0; n < 8; ++n) WmixP[base + n * 8] = v[n];
        return;
    }
    t -= NWG8;
    if (t < 2 * NW18) {   // W1 / W2: per l, 128 k x 16 col-groups
        const void* Wsrc = (t < NW18) ? W1 : W2;
        bf16_t* Wdst = (t < NW18) ? W1P : W2P;
        if (t >= NW18) t -= NW18;
        int l = t >> 11;              // /2048
        int r = t & 2047;
        int k = r >> 4;               // 0..127
        int c0 = (r & 15) * 8;
        int ks = k >> 5, kqq = (k >> 3) & 3, j = k & 7;
        int wvv = c0 >> 5, tt = (c0 >> 4) & 1, mm0 = c0 & 15;
        size_t src = (size_t)l * DIM * DIM + (size_t)k * DIM + c0;
        int base = (l << 14) + (((wvv * 4 + ks) * 2 + tt) << 9) + (kqq * 16 + mm0) * 8 + j;
        bf16_t v[8];
        read8(Wsrc, src, isbf, v);
#pragma unroll
        for (int n = 0; n < 8; ++n) Wdst[base + n * 8] = v[n];
        return;
    }
    t -= 2 * NW18;
    if (t >= 5 * NVC) return;
    int seg = t / NVC, k = t - seg * NVC;
    if (seg == 0) bgc[k] = cvt_elem(bg, k, isbf);
    else if (seg == 1) b1c[k] = cvt_elem(b1, k, isbf);
    else if (seg == 2) b2c[k] = cvt_elem(b2, k, isbf);
    else if (seg == 3) n1c[k] = cvt_elem(n1, k, isbf);
    else n2c[k] = cvt_elem(n2, k, isbf);
}

// ---------------- mega: vec-convert(+coalesced pack) + hist + asd_x8 ----------------
__global__ __launch_bounds__(256) void mega_setup(
        const void* x, const void* Wg, const void* W1, const void* W2,
        const void* bg, const void* b1, const void* b2, const void* n1, const void* n2,
        bf16_t* xb, bf16_t* WmixP, bf16_t* W1P, bf16_t* W2P,
        bf16_t* bgc, bf16_t* b1c, bf16_t* b2c, bf16_t* n1c, bf16_t* n2c,
        const int* ei, int* deg,
        const float* vS, const float* vD,
        float* a_s, float* a_d, unsigned short* x8,
        int convBlocks, int histBlocks) {
    int b = (int)blockIdx.x;
    if (b >= convBlocks + histBlocks) {   // asd_x8 part: wave per node
        bool isbf = wave_detect_bf16((const unsigned short*)x);
        int lane = threadIdx.x & 63;
        int n = (b - convBlocks - histBlocks) * 4 + (int)(threadIdx.x >> 6);
        if (n >= N_NODES) return;
        int c = 2 * lane;
        float f0 = raw_elem(x, (size_t)n * DIM + c, isbf);
        float f1 = raw_elem(x, (size_t)n * DIM + c + 1, isbf);
        x8[n * 64 + lane] = enc_fp8_pair(f0, f1);
#pragma unroll
        for (int h = 0; h < NH; ++h) {
            float ps = f0 * vS[h * DIM + c] + f1 * vS[h * DIM + c + 1];
            float pd = f0 * vD[h * DIM + c] + f1 * vD[h * DIM + c + 1];
            ps = red64(ps);
            pd = red64(pd);
            if (lane == 0) {
                a_s[n * 4 + h] = ps;
                a_d[n * 4 + h] = pd;
            }
        }
        return;
    }
    if (b >= convBlocks) {   // histogram
        bool is64 = wave_detect_i64(ei);
        int e = (b - convBlocks) * 256 + threadIdx.x;
        if (e < NEDGE) atomicAdd(&deg[edge_dst(ei, e, is64)], 1);
        return;
    }
    bool isbf = wave_detect_bf16((const unsigned short*)x);
    int i = b * 256 + threadIdx.x;
    if (i < NXV) {   // vectorized x -> bf16 convert (16B/lane)
        if (isbf) {
            ((bf16v8*)xb)[i] = ((const bf16v8*)x)[i];
        } else {
            const float4* src = (const float4*)x;
            float4 a = src[2 * i], bq = src[2 * i + 1];
            bf16v8 o;
            o[0] = (bf16_t)a.x;  o[1] = (bf16_t)a.y;
            o[2] = (bf16_t)a.z;  o[3] = (bf16_t)a.w;
            o[4] = (bf16_t)bq.x; o[5] = (bf16_t)bq.y;
            o[6] = (bf16_t)bq.z; o[7] = (bf16_t)bq.w;
            ((bf16v8*)xb)[i] = o;
        }
        return;
    }
    pack8(i - NXV, isbf, Wg, W1, W2, bg, b1, b2, n1, n2,
          WmixP, W1P, W2P, bgc, b1c, b2c, n1c, n2c);
}

// ---------------- scan: one-pass, 20 nodes per thread, 2 barriers total ----------------
__global__ __launch_bounds__(1024) void scan_kernel(const int* __restrict__ deg,
                                                    int* __restrict__ row_ptr,
                                                    int* __restrict__ cursor) {
    __shared__ int wsum[16];
    int tid = threadIdx.x, lane = tid & 63, wv = tid >> 6;
    int v[20];
    int base = tid * 20;
    int tot = 0;
    if (base < N_NODES) {
        const int4* d4 = reinterpret_cast<const int4*>(deg + base);   // 80B-aligned
#pragma unroll
        for (int j = 0; j < 5; ++j) {
            int4 q = d4[j];
            v[4 * j]     = q.x;
            v[4 * j + 1] = q.y;
            v[4 * j + 2] = q.z;
            v[4 * j + 3] = q.w;
        }
#pragma unroll
        for (int i = 0; i < 20; ++i) tot += v[i];
    }
    int x = tot;   // inclusive wave scan
#pragma unroll
    for (int off = 1; off < 64; off <<= 1) {
        int t = __shfl_up(x, off);
        if (lane >= off) x += t;
    }
    if (lane == 63) wsum[wv] = x;
    __syncthreads();
    if (wv == 0) {
        int s = (lane < 16) ? wsum[lane] : 0;
#pragma unroll
        for (int off = 1; off < 16; off <<= 1) {
            int t = __shfl_up(s, off);
            if (lane >= off) s += t;
        }
        if (lane < 16) wsum[lane] = s;
    }
    __syncthreads();
    int off0 = ((wv == 0) ? 0 : wsum[wv - 1]) + (x - tot);   // exclusive prefix of chunk
    if (tid == 0) row_ptr[0] = 0;
    if (base < N_NODES) {
        int run = off0;
#pragma unroll
        for (int i = 0; i < 20; ++i) {
            run += v[i];
            row_ptr[base + i + 1] = run;
            cursor[base + i] = run - v[i];
        }
    }
}

__global__ void fill_kernel(const int* __restrict__ ei, int* __restrict__ cursor,
                            int* __restrict__ csr_src) {
    bool is64 = wave_detect_i64(ei);
    int e = blockIdx.x * blockDim.x + threadIdx.x;
    if (e < NEDGE) {
        int d = edge_dst(ei, e, is64);
        int pos = atomicAdd(&cursor[d], 1);
        if ((unsigned)pos < (unsigned)NEDGE) csr_src[pos] = edge_src(ei, e, is64);
    }
}

__device__ __forceinline__ void acc8w(float (&acc)[8], const float4 w, unsigned short xe) {
    f32v2 f = __builtin_amdgcn_cvt_pk_f32_fp8((int)xe, false);
    acc[0] += w.x * f[0]; acc[1] += w.x * f[1];
    acc[2] += w.y * f[0]; acc[3] += w.y * f[1];
    acc[4] += w.z * f[0]; acc[5] += w.z * f[1];
    acc[6] += w.w * f[0]; acc[7] += w.w * f[1];
}

// ---- accumulate cnt (<=64) edges: weights via uniform LDS broadcast (ds_read_b128,
// proven cheap in R11), x8 row base via 1 readlane/edge (removes ssh ds_read_b32 +
// lgkm wait from the address chain). Depth-2 x8 prefetch (xA/xB static dbuf).
__device__ __forceinline__ void acc_group_loop(float (&acc)[8], int cnt,
        const float4* wshw, int sb6,
        const unsigned short* __restrict__ x8, int lane) {
    unsigned short xA[8], xB[8];
    {
        int pa = cnt < 8 ? cnt : 8;
        int pb = cnt - 8; if (pb > 8) pb = 8;
#pragma unroll
        for (int u = 0; u < 8; ++u)
            if (u < pa) xA[u] = x8[__builtin_amdgcn_readlane(sb6, u) + lane];
#pragma unroll
        for (int u = 0; u < 8; ++u)
            if (u < pb) xB[u] = x8[__builtin_amdgcn_readlane(sb6, 8 + u) + lane];
    }
    for (int u0 = 0; u0 < cnt; u0 += 16) {
        {   // consume A = group u0; refill A with group u0+16
            unsigned short xc[8];
#pragma unroll
            for (int u = 0; u < 8; ++u) xc[u] = xA[u];
            int g = u0 + 16;
            int nc = cnt - g; if (nc > 8) nc = 8;
#pragma unroll
            for (int u = 0; u < 8; ++u)
                if (u < nc) xA[u] = x8[__builtin_amdgcn_readlane(sb6, g + u) + lane];
            int uc = cnt - u0; if (uc > 8) uc = 8;
#pragma unroll
            for (int u = 0; u < 8; ++u)
                if (u < uc) acc8w(acc, wshw[u0 + u], xc[u]);   // uniform addr -> broadcast
        }
        if (u0 + 8 < cnt) {   // consume B = group u0+8; refill B with group u0+24
            unsigned short xc[8];
#pragma unroll
            for (int u = 0; u < 8; ++u) xc[u] = xB[u];
            int g = u0 + 24;
            int nc = cnt - g; if (nc > 8) nc = 8;
#pragma unroll
            for (int u = 0; u < 8; ++u)
                if (u < nc) xB[u] = x8[__builtin_amdgcn_readlane(sb6, g + u) + lane];
            int uc = cnt - (u0 + 8); if (uc > 8) uc = 8;
#pragma unroll
            for (int u = 0; u < 8; ++u)
                if (u < uc) acc8w(acc, wshw[u0 + 8 + u], xc[u]);
        }
    }
}

// ---------------- gat_phaseA: software-pipelined 4-node gather (rows chosen by caller) ----------------
// Prologue issues ALL independent front-end loads upfront; only the per-node a_s[s]
// gather is staged one-ahead. Weights staged in wsh (LDS); x8 base in registers.
__device__ __forceinline__ void gat_phaseA(int tile, int lane, const int rw[4],
        float4* wshw,
        const int* __restrict__ row_ptr, const int* __restrict__ csr_src,
        const float* __restrict__ a_s, const float* __restrict__ a_d,
        const unsigned short* __restrict__ x8, bf16_t (*ylds)[524]) {
    const float4* a_s4 = reinterpret_cast<const float4*>(a_s);
    const float4* a_d4 = reinterpret_cast<const float4*>(a_d);

    // all row_ptr loads upfront (independent)
    int beg[4], deg[4];
#pragma unroll
    for (int rp = 0; rp < 4; ++rp) {
        int nn = tile * 16 + rw[rp];
        int b = row_ptr[nn], e = row_ptr[nn + 1];
        int d = e - b;
        if (d < 0) d = 0;
        if (d > NEDGE) d = NEDGE;
        if (b < 0) b = 0;
        if (b > NEDGE - d) b = NEDGE - d;
        beg[rp] = b; deg[rp] = d;
    }

    int craw[4], sreg[4];
    unsigned short pslf[4];
    float4 av4[4], adv4[4], avs4[4];

    // prologue: ALL independent loads in flight at once
#pragma unroll
    for (int rp = 0; rp < 4; ++rp) {
        int d = deg[rp];
        int idx = (d > 0) ? (beg[rp] + (lane < d ? lane : 0)) : 0;
        craw[rp] = csr_src[idx];
    }
#pragma unroll
    for (int rp = 0; rp < 4; ++rp) {
        int nn = tile * 16 + rw[rp];
        adv4[rp] = a_d4[nn];
        avs4[rp] = a_s4[nn];
        pslf[rp] = x8[nn * 64 + lane];
    }
    {
        int s = clamp_node(craw[0]);
        sreg[0] = s;
        av4[0] = a_s4[s];           // exposed once per wave (prologue only)
    }

#pragma unroll
    for (int rp = 0; rp < 4; ++rp) {
        // ---- W(rp): weights + init (av issued >=1 stage earlier) ----
        float4 adv = adv4[rp];
        float4 a0 = av4[rp];
        float4 wl = {__expf(leaky(a0.x + adv.x)), __expf(leaky(a0.y + adv.y)),
                     __expf(leaky(a0.z + adv.z)), __expf(leaky(a0.w + adv.w))};
        float4 avs = avs4[rp];
        float4 wself = {__expf(leaky(avs.x + adv.x)), __expf(leaky(avs.y + adv.y)),
                        __expf(leaky(avs.z + adv.z)), __expf(leaky(avs.w + adv.w))};
        float acc[8];
        {
            f32v2 f = __builtin_amdgcn_cvt_pk_f32_fp8((int)pslf[rp], false);
            acc[0] = wself.x * f[0]; acc[1] = wself.x * f[1];
            acc[2] = wself.y * f[0]; acc[3] = wself.y * f[1];
            acc[4] = wself.z * f[0]; acc[5] = wself.z * f[1];
            acc[6] = wself.w * f[0]; acc[7] = wself.w * f[1];
        }
        int cnt0 = deg[rp] < 64 ? deg[rp] : 64;
        float4 zl = {0.f, 0.f, 0.f, 0.f};
        if (lane < cnt0) {
            zl = wl;
            wshw[lane] = wl;          // weight broadcast stays on LDS (proven cheap)
        }
        int sb6 = sreg[rp] << 6;      // x8 base stays in registers (readlane)

        // ---- F(rp+1): issue next node's a_s[s] gather (hides under ACC below) ----
        if (rp < 3) {
            int s = clamp_node(craw[rp + 1]);
            sreg[rp + 1] = s;
            av4[rp + 1] = a_s4[s];
        }

        // ---- ACC(rp): first chunk ----
        acc_group_loop(acc, cnt0, wshw, sb6, x8, lane);

        // ---- tail chunks (deg > 64, rare): inline front-end ----
        for (int c0 = 64; c0 < deg[rp]; c0 += 64) {
            int cnt = deg[rp] - c0; if (cnt > 64) cnt = 64;
            int sb2 = 0;
            if (lane < cnt) {
                int s = clamp_node(csr_src[beg[rp] + c0 + lane]);
                float4 a2 = a_s4[s];
                float4 w2 = {__expf(leaky(a2.x + adv.x)), __expf(leaky(a2.y + adv.y)),
                             __expf(leaky(a2.z + adv.z)), __expf(leaky(a2.w + adv.w))};
                zl.x += w2.x; zl.y += w2.y; zl.z += w2.z; zl.w += w2.w;
                wshw[lane] = w2;
                sb2 = s << 6;
            }
            acc_group_loop(acc, cnt, wshw, sb2, x8, lane);
        }

        // ---- Z-reduce (DPP) + y write ----
        float4 z4 = {wself.x + red64(zl.x), wself.y + red64(zl.y),
                     wself.z + red64(zl.z), wself.w + red64(zl.w)};
        float4 ih4 = {1.f / z4.x, 1.f / z4.y, 1.f / z4.z, 1.f / z4.w};
        int c = 2 * lane;
        bf16_t* yrow = &ylds[rw[rp]][0];
#pragma unroll
        for (int h = 0; h < NH; ++h) {
            float ih = h == 0 ? ih4.x : h == 1 ? ih4.y : h == 2 ? ih4.z : ih4.w;
            bf16v2 o;
            o[0] = (bf16_t)(acc[h * 2 + 0] * ih);
            o[1] = (bf16_t)(acc[h * 2 + 1] * ih);
            *reinterpret_cast<bf16v2*>(&yrow[h * DIM + c]) = o;
        }
    }
}

// ---------------- gat_mix: fused per-layer kernel; block = 16 nodes ----------------
// Phase A: degree-balanced pipelined 4-node gather (LDS weight broadcast + readlane x8 base).
// Phase B: proven mix+FFN with DPP 16-lane reductions.
// MODE 0: writes bf16 xb + next-layer x8/a_s/a_d.  MODE 1: writes f32 d_out.
template <int MODE>
__global__ __launch_bounds__(256) void gat_mix(
        const int* __restrict__ row_ptr, const int* __restrict__ csr_src,
        const float* __restrict__ a_s, const float* __restrict__ a_d,
        const unsigned short* __restrict__ x8,
        const bf16_t* __restrict__ WmixP, const bf16_t* __restrict__ bg,
        const bf16_t* __restrict__ n1w, const bf16_t* __restrict__ xb,
        const bf16_t* __restrict__ W1P, const bf16_t* __restrict__ b1,
        const bf16_t* __restrict__ W2P, const bf16_t* __restrict__ b2,
        const bf16_t* __restrict__ n2w, void* __restrict__ out,
        const float* __restrict__ vS, const float* __restrict__ vD,
        float* __restrict__ a_s_n, float* __restrict__ a_d_n,
        unsigned char* __restrict__ x8_n) {
    __shared__ bf16_t ylds[16][524];
    __shared__ bf16_t xm[16][140];
    __shared__ float  ssq_p[16][4];
    __shared__ float  asd_p[4][16][8];
    __shared__ float4 wsh[4][64];
    bf16_t (*hh)[140] = reinterpret_cast<bf16_t (*)[140]>(&ylds[0][0]);

    int tile = blockIdx.x;
    int wv = threadIdx.x >> 6;
    int lane = threadIdx.x & 63;
    int m = lane & 15, kq = lane >> 4;

    // ---- degree-balanced row assignment: rank 16 rows by degree (shfl), snake-deal ----
    int rw[4];
    {
        int d = 0;
        if (lane < 16) {
            int nn = tile * 16 + lane;
            d = row_ptr[nn + 1] - row_ptr[nn];
        }
        int rank = 0;
#pragma unroll
        for (int j = 0; j < 16; ++j) {
            int dj = __shfl(d, j);
            rank += ((dj > d) || (dj == d && j < lane)) ? 1 : 0;
        }
        if (lane >= 16) rank = 64;   // exclude from matches
        int tgt0 = wv, tgt1 = 7 - wv, tgt2 = 8 + wv, tgt3 = 15 - wv;
        rw[0] = __ffsll(__ballot(rank == tgt0)) - 1;
        rw[1] = __ffsll(__ballot(rank == tgt1)) - 1;
        rw[2] = __ffsll(__ballot(rank == tgt2)) - 1;
        rw[3] = __ffsll(__ballot(rank == tgt3)) - 1;
    }

    // ---- Phase A ----
    gat_phaseA(tile, lane, rw, wsh[wv], row_ptr, csr_src, a_s, a_d, x8, ylds);
    __syncthreads();

    // ---- Phase B: mix + FFN ----
    f32v4 accm[2];
    accm[0] = (f32v4){0.f, 0.f, 0.f, 0.f};
    accm[1] = (f32v4){0.f, 0.f, 0.f, 0.f};
#pragma unroll
    for (int kk = 0; kk < 16; ++kk) {
        bf16v8 a = *reinterpret_cast<const bf16v8*>(&ylds[m][kk * 32 + kq * 8]);
#pragma unroll
        for (int tt = 0; tt < 2; ++tt) {
            bf16v8 b = *reinterpret_cast<const bf16v8*>(
                WmixP + ((((wv * 16 + kk) * 2 + tt) << 9) + lane * 8));
            accm[tt] = __builtin_amdgcn_mfma_f32_16x16x32_bf16(a, b, accm[tt], 0, 0, 0);
        }
    }
    float vals[2][4];
    {
        float sp[4] = {0.f, 0.f, 0.f, 0.f};
#pragma unroll
        for (int tt = 0; tt < 2; ++tt) {
            int col = 32 * wv + tt * 16 + m;
            float bv = (float)bg[col];
#pragma unroll
            for (int r = 0; r < 4; ++r) {
                int gr = tile * 16 + kq * 4 + r;
                float v = 0.25f * accm[tt][r] + bv + (float)xb[(size_t)gr * DIM + col];
                vals[tt][r] = v;
                sp[r] += v * v;
            }
        }
#pragma unroll
        for (int r = 0; r < 4; ++r) {
            sp[r] = red16(sp[r]);
            if (m == r) ssq_p[kq * 4 + r][wv] = sp[r];
        }
    }
    __syncthreads();
    {
#pragma unroll
        for (int r = 0; r < 4; ++r) {
            int row = kq * 4 + r;
            float s = ssq_p[row][0] + ssq_p[row][1] + ssq_p[row][2] + ssq_p[row][3];
            float scale = rsqrtf(s * (1.f / 128.f) + EPS_RMS);
#pragma unroll
            for (int tt = 0; tt < 2; ++tt) {
                int col = 32 * wv + tt * 16 + m;
                xm[row][col] = (bf16_t)(vals[tt][r] * scale * (float)n1w[col]);
            }
        }
    }
    __syncthreads();

    f32v4 acc1[2];
    acc1[0] = (f32v4){0.f, 0.f, 0.f, 0.f};
    acc1[1] = (f32v4){0.f, 0.f, 0.f, 0.f};
#pragma unroll
    for (int ks = 0; ks < 4; ++ks) {
        bf16v8 a = *reinterpret_cast<const bf16v8*>(&xm[m][ks * 32 + kq * 8]);
#pragma unroll
        for (int tt = 0; tt < 2; ++tt) {
            bf16v8 b = *reinterpret_cast<const bf16v8*>(
                W1P + ((((wv * 4 + ks) * 2 + tt) << 9) + lane * 8));
            acc1[tt] = __builtin_amdgcn_mfma_f32_16x16x32_bf16(a, b, acc1[tt], 0, 0, 0);
        }
    }
#pragma unroll
    for (int tt = 0; tt < 2; ++tt) {
        int col = 32 * wv + tt * 16 + m;
        float bv = (float)b1[col];
#pragma unroll
        for (int r = 0; r < 4; ++r) {
            float v = acc1[tt][r] + bv;
            hh[kq * 4 + r][col] = (bf16_t)(v > 0.f ? v : 0.f);
        }
    }
    __syncthreads();
    f32v4 acc2[2];
    acc2[0] = (f32v4){0.f, 0.f, 0.f, 0.f};
    acc2[1] = (f32v4){0.f, 0.f, 0.f, 0.f};
#pragma unroll
    for (int ks = 0; ks < 4; ++ks) {
        bf16v8 a = *reinterpret_cast<const bf16v8*>(&hh[m][ks * 32 + kq * 8]);
#pragma unroll
        for (int tt = 0; tt < 2; ++tt) {
            bf16v8 b = *reinterpret_cast<const bf16v8*>(
                W2P + ((((wv * 4 + ks) * 2 + tt) << 9) + lane * 8));
            acc2[tt] = __builtin_amdgcn_mfma_f32_16x16x32_bf16(a, b, acc2[tt], 0, 0, 0);
        }
    }
    float vals2[2][4];
    {
        float sp[4] = {0.f, 0.f, 0.f, 0.f};
#pragma unroll
        for (int tt = 0; tt < 2; ++tt) {
            int col = 32 * wv + tt * 16 + m;
            float bv = (float)b2[col];
#pragma unroll
            for (int r = 0; r < 4; ++r) {
                float v = acc2[tt][r] + bv + (float)xm[kq * 4 + r][col];
                vals2[tt][r] = v;
                sp[r] += v * v;
            }
        }
#pragma unroll
        for (int r = 0; r < 4; ++r) {
            sp[r] = red16(sp[r]);
            if (m == r) ssq_p[kq * 4 + r][wv] = sp[r];
        }
    }
    __syncthreads();
    float o2[2][4];
#pragma unroll
    for (int r = 0; r < 4; ++r) {
        int row = kq * 4 + r;
        int gr = tile * 16 + row;
        float s = ssq_p[row][0] + ssq_p[row][1] + ssq_p[row][2] + ssq_p[row][3];
        float scale = rsqrtf(s * (1.f / 128.f) + EPS_RMS);
#pragma unroll
        for (int tt = 0; tt < 2; ++tt) {
            int col = 32 * wv + tt * 16 + m;
            float o = vals2[tt][r] * scale * (float)n2w[col];
            o2[tt][r] = o;
            if (MODE == 1) ((float*)out)[(size_t)gr * DIM + col] = o;
            else {
                ((bf16_t*)out)[(size_t)gr * DIM + col] = (bf16_t)o;
                x8_n[(size_t)gr * DIM + col] = enc_fp8(o);
            }
        }
    }
    if (MODE == 0) {
        float vs0[NH], vs1[NH], vd0[NH], vd1[NH];
        int col0 = 32 * wv + m, col1 = col0 + 16;
#pragma unroll
        for (int h = 0; h < NH; ++h) {
            vs0[h] = vS[h * DIM + col0]; vs1[h] = vS[h * DIM + col1];
            vd0[h] = vD[h * DIM + col0]; vd1[h] = vD[h * DIM + col1];
        }
#pragma unroll
        for (int r = 0; r < 4; ++r) {
#pragma unroll
            for (int h = 0; h < NH; ++h) {
                float ps = o2[0][r] * vs0[h] + o2[1][r] * vs1[h];
                float pd = o2[0][r] * vd0[h] + o2[1][r] * vd1[h];
                ps = red16(ps);
                pd = red16(pd);
                if (m == r * 4 + h) {
                    asd_p[wv][kq * 4 + r][h * 2 + 0] = ps;
                    asd_p[wv][kq * 4 + r][h * 2 + 1] = pd;
                }
            }
        }
        __syncthreads();
        int t = threadIdx.x;
        if (t < 128) {
            int row = t >> 3, idx = t & 7;
            float s = asd_p[0][row][idx] + asd_p[1][row][idx]
                    + asd_p[2][row][idx] + asd_p[3][row][idx];
            int gr = tile * 16 + row;
            if (idx & 1) a_d_n[gr * 4 + (idx >> 1)] = s;
            else         a_s_n[gr * 4 + (idx >> 1)] = s;
        }
    }
}

// ---------------- launch (7 dispatches) ----------------
extern "C" void kernel_launch(void* const* d_in, const int* in_sizes, int n_in,
                              void* d_out, int out_size, void* d_ws, size_t ws_size,
                              hipStream_t stream) {
    const void* x_in   = d_in[0];
    const void* W_gat  = d_in[1];
    const void* att_s  = d_in[2];
    const void* att_d  = d_in[3];
    const void* bias_g = d_in[4];
    const void* W1     = d_in[5];
    const void* b1     = d_in[6];
    const void* W2     = d_in[7];
    const void* b2     = d_in[8];
    const void* n1w    = d_in[9];
    const void* n2w    = d_in[10];
    const int*  ei     = (const int*)d_in[11];

    char* ws = (char*)d_ws;
    size_t off = 0;
    auto alloc = [&](size_t bytes) {
        void* p = ws + off;
        off = (off + bytes + 255) & ~(size_t)255;
        return p;
    };
    bf16_t* WmixP   = (bf16_t*)alloc((size_t)LAYERS * HD * DIM * 2);
    bf16_t* W1P     = (bf16_t*)alloc((size_t)LAYERS * DIM * DIM * 2);
    bf16_t* W2P     = (bf16_t*)alloc((size_t)LAYERS * DIM * DIM * 2);
    bf16_t* xb      = (bf16_t*)alloc((size_t)N_NODES * DIM * 2);
    unsigned short* x8a = (unsigned short*)alloc((size_t)N_NODES * DIM);
    unsigned short* x8b = (unsigned short*)alloc((size_t)N_NODES * DIM);
    float*  vS      = (float*)alloc((size_t)LAYERS * HD * 4);
    float*  vD      = (float*)alloc((size_t)LAYERS * HD * 4);
    float*  a_sA    = (float*)alloc((size_t)N_NODES * NH * 4);
    float*  a_dA    = (float*)alloc((size_t)N_NODES * NH * 4);
    float*  a_sB    = (float*)alloc((size_t)N_NODES * NH * 4);
    float*  a_dB    = (float*)alloc((size_t)N_NODES * NH * 4);
    int*    deg     = (int*)alloc((size_t)N_NODES * 4);
    int*    cursor  = (int*)alloc((size_t)N_NODES * 4);
    int*    row_ptr = (int*)alloc((size_t)(N_NODES + 1) * 4);
    int*    csr     = (int*)alloc((size_t)NEDGE * 4);
    bf16_t* bgc     = (bf16_t*)alloc((size_t)LAYERS * DIM * 2);
    bf16_t* b1c     = (bf16_t*)alloc((size_t)LAYERS * DIM * 2);
    bf16_t* b2c     = (bf16_t*)alloc((size_t)LAYERS * DIM * 2);
    bf16_t* n1c     = (bf16_t*)alloc((size_t)LAYERS * DIM * 2);
    bf16_t* n2c     = (bf16_t*)alloc((size_t)LAYERS * DIM * 2);

    // prep_v also zeroes deg (runs before mega_setup's histogram)
    prep_v<<<(LAYERS * DIM * NH * 2 * 64 + 255) / 256, 256, 0, stream>>>(
        x_in, W_gat, att_s, att_d, vS, vD, deg);

    const int NTOT = NXV + NPACK8;   // vec8 convert items + coalesced pack items
    const int convBlocks = (NTOT + 255) / 256;
    const int histBlocks = (NEDGE + 255) / 256;
    const int asdBlocks  = (N_NODES + 3) / 4;
    mega_setup<<<convBlocks + histBlocks + asdBlocks, 256, 0, stream>>>(
        x_in, W_gat, W1, W2, bias_g, b1, b2, n1w, n2w,
        xb, WmixP, W1P, W2P, bgc, b1c, b2c, n1c, n2c,
        ei, deg, vS, vD, a_sA, a_dA, x8a, convBlocks, histBlocks);

    scan_kernel<<<1, 1024, 0, stream>>>(deg, row_ptr, cursor);
    fill_kernel<<<(NEDGE + 255) / 256, 256, 0, stream>>>(ei, cursor, csr);

    unsigned short* x8cur[2] = {x8a, x8b};
    float* asCur[2] = {a_sA, a_sB};
    float* adCur[2] = {a_dA, a_dB};
    for (int l = 0; l < LAYERS; ++l) {
        int ci = l & 1, ni = (l + 1) & 1;
        if (l < LAYERS - 1) {
            gat_mix<0><<<NTILES, 256, 0, stream>>>(
                row_ptr, csr, asCur[ci], adCur[ci], x8cur[ci],
                WmixP + (size_t)l * HD * DIM, bgc + (size_t)l * DIM,
                n1c + (size_t)l * DIM, xb,
                W1P + (size_t)l * DIM * DIM, b1c + (size_t)l * DIM,
                W2P + (size_t)l * DIM * DIM, b2c + (size_t)l * DIM,
                n2c + (size_t)l * DIM, xb,
                vS + (size_t)(l + 1) * HD, vD + (size_t)(l + 1) * HD,
                asCur[ni], adCur[ni], (unsigned char*)x8cur[ni]);
        } else {
            gat_mix<1><<<NTILES, 256, 0, stream>>>(
                row_ptr, csr, asCur[ci], adCur[ci], x8cur[ci],
                WmixP + (size_t)l * HD * DIM, bgc + (size_t)l * DIM,
                n1c + (size_t)l * DIM, xb,
                W1P + (size_t)l * DIM * DIM, b1c + (size_t)l * DIM,
                W2P + (size_t)l * DIM * DIM, b2c + (size_t)l * DIM,
                n2c + (size_t)l * DIM, d_out,
                nullptr, nullptr, nullptr, nullptr, nullptr);
        }
    }
}